// Round 5
// baseline (368.776 us; speedup 1.0000x reference)
//
#include <hip/hip_runtime.h>
#include <hip/hip_bf16.h>
#include <math.h>

#define B_     32
#define HID_   768
#define OUT5_  2304
#define HDIM_  512
#define NC_    65536
#define MAXG_  11
#define NL_    670091
#define TOPK_  10
#define CAND_  110   // TOPK_*MAXG_
#define NOUT_  3520  // B_*CAND_
#define CK_    32    // k-chunk rows staged per buffer in K2
#define NMETA_ 256   // 256-col stripes
#define NEXT_  16    // ext-GEMM blocks in K2

__device__ __forceinline__ float gelu_exact(float x){
  return 0.5f * x * (1.0f + erff(x * 0.70710678118654752440f));
}

__device__ __forceinline__ unsigned long long packv(float x, int col){
  unsigned u = __float_as_uint(x);
  u = (u & 0x80000000u) ? ~u : (u | 0x80000000u);   // order-preserving float->uint
  return (((unsigned long long)u) << 16) | (unsigned long long)(65535 - col); // tie -> lower col wins
}

__device__ __forceinline__ float unpack_val(unsigned long long g){
  unsigned u = (unsigned)(g >> 16);
  unsigned bits = (u & 0x80000000u) ? (u & 0x7FFFFFFFu) : ~u;
  return __uint_as_float(bits);
}

__device__ __forceinline__ int unpack_col(unsigned long long g){
  return 65535 - (int)(g & 0xFFFFULL);
}

typedef const __attribute__((address_space(1))) void* gas_t;
typedef __attribute__((address_space(3))) void* las_t;
__device__ __forceinline__ void gload_lds16(const float* g, float* l){
  // LDS dest = wave-uniform base + lane*16; global src is per-lane.
  __builtin_amdgcn_global_load_lds((gas_t)(const void*)g, (las_t)(void*)l, 16, 0, 0);
}

// ---------------- K1: meta1 MLP: hT[j][b] = gelu(hid_first @ W1 + b1) ----------------
// 16 blocks x 256 thr; block owns 32 cols; thread: 1 col x 4 rows, full K=768.
__global__ __launch_bounds__(256)
void meta1_kernel(const float* __restrict__ hidf, const float* __restrict__ W1,
                  const float* __restrict__ b1, float* __restrict__ hT){
  const int col = blockIdx.x * 32 + (threadIdx.x & 31);
  const int r0  = (threadIdx.x >> 5) * 4;          // rows r0..r0+3
  float acc[4] = {0.f, 0.f, 0.f, 0.f};
  #pragma unroll 4
  for (int k = 0; k < HID_; ++k){
    const float w = W1[(size_t)k * HDIM_ + col];
    #pragma unroll
    for (int r = 0; r < 4; ++r)
      acc[r] = fmaf(hidf[(size_t)(r0 + r) * HID_ + k], w, acc[r]);
  }
  const float bb = b1[col];
  #pragma unroll
  for (int r = 0; r < 4; ++r)
    hT[col * B_ + r0 + r] = gelu_exact(acc[r] + bb);
}

// ---------------- K2: fused { ext GEMM (blocks 0..15) | staged meta GEMM (16..271) } ----
// 512 threads. Meta: 256-col stripe, CK=32 double-buffered LDS, wave w -> rows w*4..+4,
// lane owns cols 4l..4l+3 (ds_read_b128, dense = conflict-free).
__global__ __launch_bounds__(512)
void meta_ext(const float* __restrict__ hT, const float* __restrict__ W2,
              const float* __restrict__ b2, const float* __restrict__ hidl5,
              const float* __restrict__ Wext, const float* __restrict__ bext,
              float* __restrict__ logits, float* __restrict__ h_ext){
  __shared__ float smem[2][CK_ * 256];   // 2 x 32 KB
  const int tid = threadIdx.x;
  if (blockIdx.x < NEXT_){
    // ---- ext GEMM: h_ext = gelu(hid_last5 @ Wext + bext), 32 cols per block ----
    const int col = blockIdx.x * 32 + (tid & 31);
    const int r0  = (tid >> 5) * 2;                // rows r0, r0+1
    float acc[2] = {0.f, 0.f};
    #pragma unroll 4
    for (int k = 0; k < OUT5_; ++k){
      const float w = Wext[(size_t)k * HDIM_ + col];
      acc[0] = fmaf(hidl5[(size_t)r0 * OUT5_ + k], w, acc[0]);
      acc[1] = fmaf(hidl5[(size_t)(r0 + 1) * OUT5_ + k], w, acc[1]);
    }
    const float bb = bext[col];
    h_ext[(size_t)r0 * HDIM_ + col]       = gelu_exact(acc[0] + bb);
    h_ext[(size_t)(r0 + 1) * HDIM_ + col] = gelu_exact(acc[1] + bb);
    return;
  }
  // ---- staged meta GEMM ----
  const int l = tid & 63;
  const int w = tid >> 6;                          // 8 waves
  const int colBase = (blockIdx.x - NEXT_) * 256;
  const int sb4 = __builtin_amdgcn_readfirstlane(w * 4);   // rows sb4..sb4+3

  float acc[4][4];
  #pragma unroll
  for (int r = 0; r < 4; ++r)
    #pragma unroll
    for (int j = 0; j < 4; ++j) acc[r][j] = 0.f;

  // stage chunk c (rows c*32..+32 of stripe) into buffer bf; wave stages 4 rows.
  auto stage = [&](int c, int bf){
    #pragma unroll
    for (int i = 0; i < 4; ++i){
      const int row = c * CK_ + w * 4 + i;
      gload_lds16(W2 + (size_t)row * NC_ + colBase + l * 4,
                  &smem[bf][(w * 4 + i) * 256]);
    }
  };

  stage(0, 0);
  __syncthreads();
  int bf = 0;
  for (int c = 0; c < HDIM_ / CK_; ++c){
    if (c < HDIM_ / CK_ - 1) stage(c + 1, bf ^ 1);
    const float* hk = hT + (size_t)(c * CK_) * B_ + sb4;
    #pragma unroll 4
    for (int kk = 0; kk < CK_; ++kk){
      const float4 wv = *reinterpret_cast<const float4*>(&smem[bf][kk * 256 + l * 4]);
      const float4 hv = *reinterpret_cast<const float4*>(hk + (size_t)kk * B_);
      acc[0][0] = fmaf(hv.x, wv.x, acc[0][0]); acc[0][1] = fmaf(hv.x, wv.y, acc[0][1]);
      acc[0][2] = fmaf(hv.x, wv.z, acc[0][2]); acc[0][3] = fmaf(hv.x, wv.w, acc[0][3]);
      acc[1][0] = fmaf(hv.y, wv.x, acc[1][0]); acc[1][1] = fmaf(hv.y, wv.y, acc[1][1]);
      acc[1][2] = fmaf(hv.y, wv.z, acc[1][2]); acc[1][3] = fmaf(hv.y, wv.w, acc[1][3]);
      acc[2][0] = fmaf(hv.z, wv.x, acc[2][0]); acc[2][1] = fmaf(hv.z, wv.y, acc[2][1]);
      acc[2][2] = fmaf(hv.z, wv.z, acc[2][2]); acc[2][3] = fmaf(hv.z, wv.w, acc[2][3]);
      acc[3][0] = fmaf(hv.w, wv.x, acc[3][0]); acc[3][1] = fmaf(hv.w, wv.y, acc[3][1]);
      acc[3][2] = fmaf(hv.w, wv.z, acc[3][2]); acc[3][3] = fmaf(hv.w, wv.w, acc[3][3]);
    }
    __syncthreads();
    bf ^= 1;
  }

  const float4 bb = *reinterpret_cast<const float4*>(b2 + colBase + l * 4);
  #pragma unroll
  for (int r = 0; r < 4; ++r){
    float4 o;
    o.x = acc[r][0] + bb.x; o.y = acc[r][1] + bb.y;
    o.z = acc[r][2] + bb.z; o.w = acc[r][3] + bb.w;
    *reinterpret_cast<float4*>(logits + (size_t)(sb4 + r) * NC_ + colBase + l * 4) = o;
  }
}

// ---------------- K3: per-row top-10 + candidate gather/dot + all outputs ---------------
// 32 blocks (one per batch row) x 1024 thr (16 waves).
__global__ __launch_bounds__(1024)
void topk_cand(const float* __restrict__ logits, const int* __restrict__ gy,
               const float* __restrict__ embed, const float* __restrict__ h_ext,
               float* __restrict__ out_f){
  __shared__ unsigned long long sm[16];
  __shared__ int   tk_i[TOPK_];
  __shared__ float tk_s[TOPK_];
  const int b    = blockIdx.x;
  const int tid  = threadIdx.x;
  const int lane = tid & 63;
  const int w    = tid >> 6;                        // 0..15

  // Phase A: per-thread sorted top-10 over 64 strided elements.
  const float* row = logits + (size_t)b * NC_;
  float v[10]; int ix[10];
  #pragma unroll
  for (int r = 0; r < 10; ++r){ v[r] = -INFINITY; ix[r] = -1; }
  for (int i = 0; i < 64; ++i){
    const int j = i * 1024 + tid;
    const float x = row[j];
    if (x > v[9]){
      v[9] = x; ix[9] = j;
      #pragma unroll
      for (int p = 9; p > 0; --p){
        if (v[p] > v[p-1]){
          float tv = v[p]; v[p] = v[p-1]; v[p-1] = tv;
          int   ti = ix[p]; ix[p] = ix[p-1]; ix[p-1] = ti;
        }
      }
    }
  }
  // 10 rounds of block-max over 16 waves; winner records its entry.
  for (int r = 0; r < 10; ++r){
    unsigned long long m = (ix[0] >= 0) ? packv(v[0], ix[0]) : 0ULL;
    unsigned long long wm = m;
    #pragma unroll
    for (int off = 1; off < 64; off <<= 1){
      unsigned long long o = __shfl_xor(wm, off);
      if (o > wm) wm = o;
    }
    if (lane == 0) sm[w] = wm;
    __syncthreads();
    unsigned long long g = sm[0];
    #pragma unroll
    for (int q = 1; q < 16; ++q) if (sm[q] > g) g = sm[q];
    if (m == g && g != 0ULL){                      // unique owner (col in key)
      tk_i[r] = unpack_col(g);
      tk_s[r] = 1.0f / (1.0f + expf(-unpack_val(g)));
      #pragma unroll
      for (int q = 0; q < 9; ++q){ v[q] = v[q+1]; ix[q] = ix[q+1]; }
      v[9] = -INFINITY; ix[9] = -1;
    }
    __syncthreads();
  }

  // Phase B: wave w handles candidate slots c = w, w+16, ...
  const unsigned int* gyw = (const unsigned int*)gy;
  const unsigned int probe = gyw[2 * (size_t)((b * 16 + w) * 64 + lane) + 1];
  const bool is64 = (__ballot(probe != 0u) == 0ULL);  // int64 vs int32 group_y

  const float* hrow = h_ext + (size_t)b * HDIM_;
  const float4 h0 = reinterpret_cast<const float4*>(hrow)[lane];
  const float4 h1 = reinterpret_cast<const float4*>(hrow)[lane + 64];
  __hip_bfloat16* outs = (__hip_bfloat16*)(out_f + NOUT_);
  __hip_bfloat16* outm = outs + NOUT_;

  for (int c = w; c < CAND_; c += 16){
    const int t = c / MAXG_;
    const int g = c - t * MAXG_;
    const int idx = tk_i[t];
    const size_t li = (size_t)idx * MAXG_ + g;
    const int cand = is64 ? (int)((const long long*)gy)[li] : gy[li];
    const float* erow = embed + (size_t)cand * HDIM_;
    const float4 e0 = reinterpret_cast<const float4*>(erow)[lane];
    const float4 e1 = reinterpret_cast<const float4*>(erow)[lane + 64];
    float s = e0.x*h0.x + e0.y*h0.y + e0.z*h0.z + e0.w*h0.w
            + e1.x*h1.x + e1.y*h1.y + e1.z*h1.z + e1.w*h1.w;
    #pragma unroll
    for (int off = 1; off < 64; off <<= 1) s += __shfl_xor(s, off);
    if (lane == 0){
      const float cs   = (s == 0.0f) ? 0.0f : 1.0f / (1.0f + expf(-s));
      const float comb = cs * ((cand != NL_) ? tk_s[t] : 0.0f);
      const int o = b * CAND_ + c;
      out_f[o] = (float)cand;
      outs[o]  = __float2bfloat16(cs);
      outm[o]  = __float2bfloat16(comb);
    }
  }
}

extern "C" void kernel_launch(void* const* d_in, const int* in_sizes, int n_in,
                              void* d_out, int out_size, void* d_ws, size_t ws_size,
                              hipStream_t stream){
  const float* hidf  = (const float*)d_in[0];
  const float* hidl5 = (const float*)d_in[1];
  const float* W1    = (const float*)d_in[2];
  const float* b1    = (const float*)d_in[3];
  const float* W2    = (const float*)d_in[4];
  const float* b2    = (const float*)d_in[5];
  const float* Wext  = (const float*)d_in[6];
  const float* bext  = (const float*)d_in[7];
  const float* embed = (const float*)d_in[8];
  const int*   gy    = (const int*)d_in[9];
  float* out_f = (float*)d_out;

  float* ws     = (float*)d_ws;
  float* logits = ws;                            // [32][65536] f32 (8 MiB)
  float* hT     = logits + (size_t)B_ * NC_;     // [512][32]
  float* h_ext  = hT + B_ * HDIM_;               // [32][512]

  meta1_kernel<<<16, 256, 0, stream>>>(hidf, W1, b1, hT);
  meta_ext   <<<NEXT_ + NMETA_, 512, 0, stream>>>(hT, W2, b2, hidl5, Wext, bext,
                                                  logits, h_ext);
  topk_cand  <<<B_, 1024, 0, stream>>>(logits, gy, embed, h_ext, out_f);
}

// Round 6
// 183.679 us; speedup vs baseline: 2.0077x; 2.0077x over previous
//
#include <hip/hip_runtime.h>
#include <hip/hip_bf16.h>
#include <math.h>

#define B_     32
#define HID_   768
#define OUT5_  2304
#define HDIM_  512
#define NC_    65536
#define MAXG_  11
#define NL_    670091
#define TOPK_  10
#define CAND_  110   // TOPK_*MAXG_
#define NOUT_  3520  // B_*CAND_
#define CK_    32    // W2 k-rows per staged buffer
#define NMETA_ 256   // 256-col stripes (65536/256)

__device__ __forceinline__ float gelu_exact(float x){
  return 0.5f * x * (1.0f + erff(x * 0.70710678118654752440f));
}

__device__ __forceinline__ unsigned long long packv(float x, int col){
  unsigned u = __float_as_uint(x);
  u = (u & 0x80000000u) ? ~u : (u | 0x80000000u);   // order-preserving float->uint
  return (((unsigned long long)u) << 16) | (unsigned long long)(65535 - col); // tie -> lower col
}

__device__ __forceinline__ float unpack_val(unsigned long long g){
  unsigned u = (unsigned)(g >> 16);
  unsigned bits = (u & 0x80000000u) ? (u & 0x7FFFFFFFu) : ~u;
  return __uint_as_float(bits);
}

__device__ __forceinline__ int unpack_col(unsigned long long g){
  return 65535 - (int)(g & 0xFFFFULL);
}

typedef const __attribute__((address_space(1))) void* gas_t;
typedef __attribute__((address_space(3))) void* las_t;
__device__ __forceinline__ void gload_lds16(const float* g, float* l){
  // LDS dest = wave-uniform base + lane*16; global src is per-lane.
  __builtin_amdgcn_global_load_lds((gas_t)(const void*)g, (las_t)(void*)l, 16, 0, 0);
}

// ---- K1: partial sums for both small GEMMs (k-chunked, high TLP; proven round-4) ----
// grid (8,16): x = 64-col tile; y<4 -> meta1 chunks (4x192=768), y>=4 -> ext (12x192=2304)
__global__ __launch_bounds__(256)
void mlp_partial(const float* __restrict__ hidf, const float* __restrict__ hidl5,
                 const float* __restrict__ W1, const float* __restrict__ Wext,
                 float* __restrict__ partial){
  const int jl  = threadIdx.x & 63;
  const int bq  = threadIdx.x >> 6;
  const int col = blockIdx.x * 64 + jl;
  const int chunk = blockIdx.y;
  const float* W; const float* X; int Kfull, k0;
  if (chunk < 4){ W = W1;   X = hidf;  Kfull = HID_;  k0 = chunk * 192; }
  else          { W = Wext; X = hidl5; Kfull = OUT5_; k0 = (chunk - 4) * 192; }
  const float* Wp = W + (size_t)k0 * HDIM_ + col;
  const float* Xp = X + (size_t)(bq * 8) * Kfull + k0;
  float acc[8] = {0,0,0,0,0,0,0,0};
  for (int k = 0; k < 192; ++k){
    float w = Wp[(size_t)k * HDIM_];
    #pragma unroll
    for (int i = 0; i < 8; ++i)
      acc[i] = fmaf(Xp[(size_t)i * Kfull + k], w, acc[i]);
  }
  float* outp = partial + (size_t)chunk * (B_ * HDIM_) + (size_t)(bq * 8) * HDIM_ + col;
  #pragma unroll
  for (int i = 0; i < 8; ++i) outp[(size_t)i * HDIM_] = acc[i];
}

// ---- K2: meta GEMM. Prologue: reduce meta1 partials -> swizzled hT in LDS.
// Then staged W2 double-buffer (CK=32) k-loop. 256 blocks x 512 thr, 128 KB LDS.
__global__ __launch_bounds__(512)
void meta_gemm2(const float* __restrict__ partial, const float* __restrict__ b1,
                const float* __restrict__ W2, const float* __restrict__ b2,
                float* __restrict__ logits){
  __shared__ float hTl[HDIM_ * B_];        // 64 KB, [j][b ^ ((j&7)<<2)]
  __shared__ float smem[2][CK_ * 256];     // 64 KB
  const int tid = threadIdx.x;
  const int l   = tid & 63;
  const int w   = tid >> 6;                // 8 waves
  const int colBase = blockIdx.x * 256;

  // prologue: hT[j][b] = gelu(b1[j] + sum_c partial[c][b][j]); j = tid
  {
    const float bias1 = b1[tid];
    for (int b = 0; b < B_; ++b){
      float s = bias1;
      #pragma unroll
      for (int c = 0; c < 4; ++c) s += partial[c * (B_ * HDIM_) + b * HDIM_ + tid];
      hTl[tid * B_ + (b ^ ((tid & 7) << 2))] = gelu_exact(s);
    }
  }

  const int sb4 = __builtin_amdgcn_readfirstlane((tid >> 6) * 4);  // rows sb4..sb4+3

  float acc[4][4];
  #pragma unroll
  for (int r = 0; r < 4; ++r)
    #pragma unroll
    for (int j = 0; j < 4; ++j) acc[r][j] = 0.f;

  auto stage = [&](int c, int bf){
    #pragma unroll
    for (int i = 0; i < 4; ++i){
      const int row = c * CK_ + w * 4 + i;
      gload_lds16(W2 + (size_t)row * NC_ + colBase + l * 4,
                  &smem[bf][(w * 4 + i) * 256]);
    }
  };

  stage(0, 0);
  __syncthreads();     // hTl visible + stage(0) drained
  int bf = 0;
  for (int c = 0; c < HDIM_ / CK_; ++c){
    if (c < HDIM_ / CK_ - 1) stage(c + 1, bf ^ 1);
    #pragma unroll
    for (int g = 0; g < 4; ++g){
      float4 hv[8];
      #pragma unroll
      for (int q = 0; q < 8; ++q){
        const int kg = c * CK_ + g * 8 + q;
        hv[q] = *reinterpret_cast<const float4*>(&hTl[kg * B_ + (sb4 ^ ((kg & 7) << 2))]);
      }
      #pragma unroll
      for (int q = 0; q < 8; ++q){
        const int kk = g * 8 + q;
        const float4 wv = *reinterpret_cast<const float4*>(&smem[bf][kk * 256 + l * 4]);
        acc[0][0] = fmaf(hv[q].x, wv.x, acc[0][0]); acc[0][1] = fmaf(hv[q].x, wv.y, acc[0][1]);
        acc[0][2] = fmaf(hv[q].x, wv.z, acc[0][2]); acc[0][3] = fmaf(hv[q].x, wv.w, acc[0][3]);
        acc[1][0] = fmaf(hv[q].y, wv.x, acc[1][0]); acc[1][1] = fmaf(hv[q].y, wv.y, acc[1][1]);
        acc[1][2] = fmaf(hv[q].y, wv.z, acc[1][2]); acc[1][3] = fmaf(hv[q].y, wv.w, acc[1][3]);
        acc[2][0] = fmaf(hv[q].z, wv.x, acc[2][0]); acc[2][1] = fmaf(hv[q].z, wv.y, acc[2][1]);
        acc[2][2] = fmaf(hv[q].z, wv.z, acc[2][2]); acc[2][3] = fmaf(hv[q].z, wv.w, acc[2][3]);
        acc[3][0] = fmaf(hv[q].w, wv.x, acc[3][0]); acc[3][1] = fmaf(hv[q].w, wv.y, acc[3][1]);
        acc[3][2] = fmaf(hv[q].w, wv.z, acc[3][2]); acc[3][3] = fmaf(hv[q].w, wv.w, acc[3][3]);
      }
    }
    __syncthreads();
    bf ^= 1;
  }

  const float4 bb = *reinterpret_cast<const float4*>(b2 + colBase + l * 4);
  #pragma unroll
  for (int r = 0; r < 4; ++r){
    float4 o;
    o.x = acc[r][0] + bb.x; o.y = acc[r][1] + bb.y;
    o.z = acc[r][2] + bb.z; o.w = acc[r][3] + bb.w;
    *reinterpret_cast<float4*>(logits + (size_t)(sb4 + r) * NC_ + colBase + l * 4) = o;
  }
}

// ---- K3: per-row { ext-partial reduce -> h_ext LDS | top-10 | candidates } ----
// 32 blocks x 1024 thr (16 waves).
__global__ __launch_bounds__(1024)
void topk_cand(const float* __restrict__ logits, const float* __restrict__ partial,
               const float* __restrict__ bext, const int* __restrict__ gy,
               const float* __restrict__ embed, float* __restrict__ out_f){
  __shared__ float hextl[HDIM_];
  __shared__ unsigned long long sm[16];
  __shared__ int   tk_i[TOPK_];
  __shared__ float tk_s[TOPK_];
  const int b    = blockIdx.x;
  const int tid  = threadIdx.x;
  const int lane = tid & 63;
  const int w    = tid >> 6;                        // 0..15

  // prologue: h_ext row b from ext partials
  if (tid < HDIM_){
    float s = bext[tid];
    #pragma unroll
    for (int c = 4; c < 16; ++c) s += partial[c * (B_ * HDIM_) + b * HDIM_ + tid];
    hextl[tid] = gelu_exact(s);
  }
  __syncthreads();

  // Phase A: per-thread sorted top-10 over 64 strided elements, then 10 block-max rounds.
  const float* row = logits + (size_t)b * NC_;
  float v[10]; int ix[10];
  #pragma unroll
  for (int r = 0; r < 10; ++r){ v[r] = -INFINITY; ix[r] = -1; }
  for (int i = 0; i < 64; ++i){
    const int j = i * 1024 + tid;
    const float x = row[j];
    if (x > v[9]){
      v[9] = x; ix[9] = j;
      #pragma unroll
      for (int p = 9; p > 0; --p){
        if (v[p] > v[p-1]){
          float tv = v[p]; v[p] = v[p-1]; v[p-1] = tv;
          int   ti = ix[p]; ix[p] = ix[p-1]; ix[p-1] = ti;
        }
      }
    }
  }
  for (int r = 0; r < 10; ++r){
    unsigned long long m = (ix[0] >= 0) ? packv(v[0], ix[0]) : 0ULL;
    unsigned long long wm = m;
    #pragma unroll
    for (int off = 1; off < 64; off <<= 1){
      unsigned long long o = __shfl_xor(wm, off);
      if (o > wm) wm = o;
    }
    if (lane == 0) sm[w] = wm;
    __syncthreads();
    unsigned long long g = sm[0];
    #pragma unroll
    for (int q = 1; q < 16; ++q) if (sm[q] > g) g = sm[q];
    if (m == g && g != 0ULL){                      // unique owner (col in key)
      tk_i[r] = unpack_col(g);
      tk_s[r] = 1.0f / (1.0f + expf(-unpack_val(g)));
      #pragma unroll
      for (int q = 0; q < 9; ++q){ v[q] = v[q+1]; ix[q] = ix[q+1]; }
      v[9] = -INFINITY; ix[9] = -1;
    }
    __syncthreads();
  }

  // Phase B: wave w handles candidate slots c = w, w+16, ...
  const unsigned int* gyw = (const unsigned int*)gy;
  const unsigned int probe = gyw[2 * (size_t)((b * 16 + w) * 64 + lane) + 1];
  const bool is64 = (__ballot(probe != 0u) == 0ULL);  // int64 vs int32 group_y

  const float4 h0 = *reinterpret_cast<const float4*>(&hextl[lane * 4]);
  const float4 h1 = *reinterpret_cast<const float4*>(&hextl[256 + lane * 4]);
  __hip_bfloat16* outs = (__hip_bfloat16*)(out_f + NOUT_);
  __hip_bfloat16* outm = outs + NOUT_;

  for (int c = w; c < CAND_; c += 16){
    const int t = c / MAXG_;
    const int g = c - t * MAXG_;
    const int idx = tk_i[t];
    const size_t li = (size_t)idx * MAXG_ + g;
    const int cand = is64 ? (int)((const long long*)gy)[li] : gy[li];
    const float* erow = embed + (size_t)cand * HDIM_;
    const float4 e0 = reinterpret_cast<const float4*>(erow)[lane];
    const float4 e1 = reinterpret_cast<const float4*>(erow)[lane + 64];
    float s = e0.x*h0.x + e0.y*h0.y + e0.z*h0.z + e0.w*h0.w
            + e1.x*h1.x + e1.y*h1.y + e1.z*h1.z + e1.w*h1.w;
    #pragma unroll
    for (int off = 1; off < 64; off <<= 1) s += __shfl_xor(s, off);
    if (lane == 0){
      const float cs   = (s == 0.0f) ? 0.0f : 1.0f / (1.0f + expf(-s));
      const float comb = cs * ((cand != NL_) ? tk_s[t] : 0.0f);
      const int o = b * CAND_ + c;
      out_f[o] = (float)cand;
      outs[o]  = __float2bfloat16(cs);
      outm[o]  = __float2bfloat16(comb);
    }
  }
}

extern "C" void kernel_launch(void* const* d_in, const int* in_sizes, int n_in,
                              void* d_out, int out_size, void* d_ws, size_t ws_size,
                              hipStream_t stream){
  const float* hidf  = (const float*)d_in[0];
  const float* hidl5 = (const float*)d_in[1];
  const float* W1    = (const float*)d_in[2];
  const float* b1    = (const float*)d_in[3];
  const float* W2    = (const float*)d_in[4];
  const float* b2    = (const float*)d_in[5];
  const float* Wext  = (const float*)d_in[6];
  const float* bext  = (const float*)d_in[7];
  const float* embed = (const float*)d_in[8];
  const int*   gy    = (const int*)d_in[9];
  float* out_f = (float*)d_out;

  float* ws      = (float*)d_ws;
  float* logits  = ws;                             // [32][65536] f32 (8 MiB)
  float* partial = logits + (size_t)B_ * NC_;      // 16 x [32][512] f32 (1 MiB), NOT aliased

  mlp_partial<<<dim3(8, 16), 256, 0, stream>>>(hidf, hidl5, W1, Wext, partial);
  meta_gemm2 <<<NMETA_, 512, 0, stream>>>(partial, b1, W2, b2, logits);
  topk_cand  <<<B_, 1024, 0, stream>>>(logits, partial, bext, gy, embed, out_f);
}